// Round 5
// baseline (397.228 us; speedup 1.0000x reference)
//
#include <hip/hip_runtime.h>

#define Cc  256
#define Hh  96
#define Ww  96
#define HW  (Hh*Ww)          // 9216
#define OC  32
#define HS  192
#define WSS 192
#define PLANE (HS*WSS)       // 36864
#define WT_FLOATS (Cc*OC)    // 8192

typedef float f32x2 __attribute__((ext_vector_type(2)));

// Kernel 0: transpose w [32][256] -> wt [256][32] so K1 can s_load contiguous
// 128B rows of weights into SGPRs. 8192 floats, ~2 us.
__global__ __launch_bounds__(256) void transpose_w_kernel(
    const float* __restrict__ w, float* __restrict__ wt)
{
    const int l = blockIdx.x * 256 + threadIdx.x;   // 8192 exactly
    const int o = l >> 8, c = l & 255;
    wt[c * OC + o] = w[l];
}

// Kernel 1: 1x1 conv (C=256 -> 32) + pixel_shuffle(2) + tanh + grid build.
// R5 rewrite: 2 pixels per lane (f32x2 loads -> 512B/wave-instr DRAM bursts,
// half the request count), v_pk_fma_f32 inner loop, unroll 4 (4 x 512B in
// flight per thread). 4 waves/block = 4 x 64-channel slices over the same
// 128 pixels; f32x2 partials reduced through 64 KB LDS. Weights via
// wave-uniform s_load (zero ds_read in inner loop). Per-pixel FP order
// identical to previous version (bit-identical output).
__global__ __launch_bounds__(256) void conv_offset_kernel(
    const float* __restrict__ x, const float* __restrict__ wt,
    const float* __restrict__ bias, float* __restrict__ grid_buf)
{
    __shared__ f32x2 lds[Cc * OC];   // 64 KB: partials [o*4+slice][lane]
    const int tid   = threadIdx.x;
    const int lane  = tid & 63;
    const int slice = __builtin_amdgcn_readfirstlane(tid >> 6); // wave-uniform

    const int pixbase = blockIdx.x * 128;     // 576 blocks, 128 px each
    const int b   = pixbase / HW;             // HW % 128 == 0: no b-split
    const int hw0 = pixbase - b * HW + 2 * lane;   // lane's first pixel (even)
    const float* xp = x + (size_t)b * Cc * HW + (size_t)(slice * 64) * HW + hw0;
    const float* wp = wt + slice * (64 * OC); // wave-uniform base -> s_load

    f32x2 acc[OC];
    #pragma unroll
    for (int o = 0; o < OC; ++o) acc[o] = (f32x2){0.0f, 0.0f};

    #pragma unroll 4
    for (int c = 0; c < 64; ++c) {
        f32x2 xv = __builtin_nontemporal_load((const f32x2*)(xp + (size_t)c * HW));
        const float4* w4 = (const float4*)&wp[c * OC];  // uniform -> s_load
        #pragma unroll
        for (int o4 = 0; o4 < 8; ++o4) {
            float4 wv = w4[o4];
            acc[4*o4+0] = acc[4*o4+0] + xv * wv.x;   // v_pk_fma_f32
            acc[4*o4+1] = acc[4*o4+1] + xv * wv.y;
            acc[4*o4+2] = acc[4*o4+2] + xv * wv.z;
            acc[4*o4+3] = acc[4*o4+3] + xv * wv.w;
        }
    }

    // partial exchange: lds[(o*4 + slice)*64 + lane], 8B lane stride (2-way, free)
    #pragma unroll
    for (int o = 0; o < OC; ++o) lds[(o * 4 + slice) * 64 + lane] = acc[o];
    __syncthreads();

    // each thread finishes 8 outputs x its 2 pixels: o in [slice*8, slice*8+8)
    const int h   = hw0 / Ww;                 // both pixels same row (hw0 even)
    const int ww0 = hw0 - h * Ww;
    const int obase = slice * 8;
    #pragma unroll
    for (int oo = 0; oo < 8; ++oo) {
        const int o = obase + oo;
        f32x2 p0 = lds[(o * 4 + 0) * 64 + lane];
        f32x2 p1 = lds[(o * 4 + 1) * 64 + lane];
        f32x2 p2 = lds[(o * 4 + 2) * 64 + lane];
        f32x2 p3 = lds[(o * 4 + 3) * 64 + lane];
        const float bo = bias[o];
        f32x2 s2 = ((p0 + p1) + p2) + p3;     // same add order as before
        // o = co*4 + i*2 + j ; co = gr*2 + k (k: 0 = x-coord, 1 = y-coord)
        const int co  = o >> 2;
        const int rem = o & 3;
        const int i   = rem >> 1;
        const int j   = rem & 1;
        const int gr  = co >> 1;
        const int k   = co & 1;
        const int hs  = 2 * h + i;
        const int bg  = b * 4 + gr;
        #pragma unroll
        for (int j2 = 0; j2 < 2; ++j2) {
            float s = (j2 == 0 ? s2.x : s2.y) + bo;
            const int ws = 2 * (ww0 + j2) + j;
            float t = tanhf(s);
            // absolute source coord: (grid_norm + 1)*48 - 0.5
            float coord = (k == 0) ? (0.5f * (float)ws - 0.25f + 6.0f * t)
                                   : (0.5f * (float)hs - 0.25f + 6.0f * t);
            coord = fminf(fmaxf(coord, 0.0f), 95.0f);   // border clamp
            grid_buf[(((size_t)bg * HS + hs) * WSS + ws) * 2 + k] = coord;
        }
    }
}

// Kernel 2: bilinear gather, FOUR channels of the same group per block with
// the planes interleaved as float4 in LDS (149.5 KB -> 1 block/CU, 1024
// threads = 16 waves/CU). Each lane handles 2 consecutive output positions
// x 4 channels per iteration. (unchanged from R4 for clean attribution)
__global__ __launch_bounds__(1024) void sample_kernel(
    const float* __restrict__ x, const float* __restrict__ grid_buf,
    float* __restrict__ out)
{
    __shared__ __align__(16) float4 pl[9344];   // 9216 interleaved + 128 pad
    const int bq  = blockIdx.x;          // b*64 + (c>>2)
    const int b   = bq >> 6;
    const int c4  = (bq & 63) << 2;      // channels c4..c4+3 (same group)
    const int bg  = b * 4 + (c4 >> 6);
    const int tid = threadIdx.x;

    const float* x0 = x + (size_t)(b * 256 + c4) * HW;
    #pragma unroll
    for (int i = 0; i < 9; ++i) {
        int t = tid + 1024 * i;                    // 9216 exactly
        float a = __builtin_nontemporal_load(x0 + t);
        float bb = __builtin_nontemporal_load(x0 + HW + t);
        float cc = __builtin_nontemporal_load(x0 + 2 * HW + t);
        float dd = __builtin_nontemporal_load(x0 + 3 * HW + t);
        pl[t] = make_float4(a, bb, cc, dd);        // 16B lane stride: no conflict
    }
    if (tid < 128) pl[9216 + tid] = make_float4(0.f, 0.f, 0.f, 0.f); // border pad
    __syncthreads();

    const float* gbase = grid_buf + (size_t)bg * PLANE * 2;
    float* ob = out + (size_t)(b * 256 + c4) * PLANE;

    #pragma unroll 2
    for (int r = 0; r < 18; ++r) {
        const int idx = r * 2048 + tid * 2;        // 2 consecutive positions
        float4 g = *(const float4*)(gbase + (size_t)idx * 2);  // gx0,gy0,gx1,gy1
        float4 r0, r1;
        {   // position 0
            float x0f = floorf(g.x), y0f = floorf(g.y);
            float wx = g.x - x0f, wy = g.y - y0f;
            int base = (int)fmaf(y0f, 96.0f, x0f);
            float4 a0 = pl[base],      a1 = pl[base + 1];
            float4 b0 = pl[base + 96], b1 = pl[base + 97];
            float tx, bx;
            tx = a0.x + (a1.x - a0.x) * wx; bx = b0.x + (b1.x - b0.x) * wx; r0.x = tx + (bx - tx) * wy;
            tx = a0.y + (a1.y - a0.y) * wx; bx = b0.y + (b1.y - b0.y) * wx; r0.y = tx + (bx - tx) * wy;
            tx = a0.z + (a1.z - a0.z) * wx; bx = b0.z + (b1.z - b0.z) * wx; r0.z = tx + (bx - tx) * wy;
            tx = a0.w + (a1.w - a0.w) * wx; bx = b0.w + (b1.w - b0.w) * wx; r0.w = tx + (bx - tx) * wy;
        }
        {   // position 1
            float x0f = floorf(g.z), y0f = floorf(g.w);
            float wx = g.z - x0f, wy = g.w - y0f;
            int base = (int)fmaf(y0f, 96.0f, x0f);
            float4 a0 = pl[base],      a1 = pl[base + 1];
            float4 b0 = pl[base + 96], b1 = pl[base + 97];
            float tx, bx;
            tx = a0.x + (a1.x - a0.x) * wx; bx = b0.x + (b1.x - b0.x) * wx; r1.x = tx + (bx - tx) * wy;
            tx = a0.y + (a1.y - a0.y) * wx; bx = b0.y + (b1.y - b0.y) * wx; r1.y = tx + (bx - tx) * wy;
            tx = a0.z + (a1.z - a0.z) * wx; bx = b0.z + (b1.z - b0.z) * wx; r1.z = tx + (bx - tx) * wy;
            tx = a0.w + (a1.w - a0.w) * wx; bx = b0.w + (b1.w - b0.w) * wx; r1.w = tx + (bx - tx) * wy;
        }
        f32x2 s0 = {r0.x, r1.x};
        f32x2 s1 = {r0.y, r1.y};
        f32x2 s2 = {r0.z, r1.z};
        f32x2 s3 = {r0.w, r1.w};
        __builtin_nontemporal_store(s0, (f32x2*)(ob + idx));
        __builtin_nontemporal_store(s1, (f32x2*)(ob + PLANE + idx));
        __builtin_nontemporal_store(s2, (f32x2*)(ob + 2 * PLANE + idx));
        __builtin_nontemporal_store(s3, (f32x2*)(ob + 3 * PLANE + idx));
    }
}

extern "C" void kernel_launch(void* const* d_in, const int* in_sizes, int n_in,
                              void* d_out, int out_size, void* d_ws, size_t ws_size,
                              hipStream_t stream) {
    const float* x    = (const float*)d_in[0];
    const float* w    = (const float*)d_in[1];
    const float* bias = (const float*)d_in[2];
    float* out        = (float*)d_out;
    float* wt         = (float*)d_ws;                 // 32 KB transposed weights
    float* grid_buf   = wt + WT_FLOATS;               // 9.4 MB grid coords

    transpose_w_kernel<<<32, 256, 0, stream>>>(w, wt);
    conv_offset_kernel<<<576, 256, 0, stream>>>(x, wt, bias, grid_buf);
    sample_kernel<<<512, 1024, 0, stream>>>(x, grid_buf, out);
}